// Round 11
// baseline (313.670 us; speedup 1.0000x reference)
//
#include <hip/hip_runtime.h>
#include <hip/hip_bf16.h>
#include <math.h>

// ---- model constants ----
constexpr int Bb = 4, Ls = 1024, DM = 512, DI = 1024, NH = 16, HD = 64, DS = 64;
constexpr int CDIM = DI + 2 * DS;          // 1152
constexpr int DIP  = 2 * DI + 2 * DS + NH; // 2192
constexpr int NPJ  = 2 * DI + 2 * DS;      // 2176 = 17*128
constexpr float EPSf = 1e-5f;
constexpr int TOK = Bb * Ls;               // 4096
constexpr int CH = 64, NCH = Ls / CH;      // 16 chunks of 64

#define DEVI __device__ __forceinline__

using bfrag = __attribute__((ext_vector_type(8))) short;
using f4v   = __attribute__((ext_vector_type(4))) float;
using u16x8 = __attribute__((ext_vector_type(8))) unsigned short;

#define GLOAD16(gp, lp)                                                              \
  __builtin_amdgcn_global_load_lds((__attribute__((address_space(1))) void*)(gp),   \
                                   (__attribute__((address_space(3))) void*)(lp),   \
                                   16, 0, 0)

DEVI float wsum(float v) {
#pragma unroll
  for (int o = 32; o > 0; o >>= 1) v += __shfl_xor(v, o);
  return v;
}
DEVI float sigmoidf_(float x) { return 1.f / (1.f + __expf(-x)); }
DEVI unsigned short f2bf(float x) {
  union { float f; unsigned u; } c{x};
  unsigned u = c.u;
  u += 0x7fffu + ((u >> 16) & 1u);
  return (unsigned short)(u >> 16);
}
DEVI float bf2f(unsigned short u) {
  union { unsigned u; float f; } c{(unsigned)u << 16};
  return c.f;
}

DEVI void ld8(const float* __restrict__ p, int lane, float (&x)[8]) {
  float4 a = *(const float4*)(p + lane * 4);
  float4 b = *(const float4*)(p + 256 + lane * 4);
  x[0] = a.x; x[1] = a.y; x[2] = a.z; x[3] = a.w;
  x[4] = b.x; x[5] = b.y; x[6] = b.z; x[7] = b.w;
}
DEVI void ld8bf(const unsigned short* __restrict__ p, int lane, float (&x)[8]) {
  ushort4 a = *(const ushort4*)(p + lane * 4);
  ushort4 b = *(const ushort4*)(p + 256 + lane * 4);
  x[0] = bf2f(a.x); x[1] = bf2f(a.y); x[2] = bf2f(a.z); x[3] = bf2f(a.w);
  x[4] = bf2f(b.x); x[5] = bf2f(b.y); x[6] = bf2f(b.z); x[7] = bf2f(b.w);
}
DEVI void st8(float* __restrict__ p, int lane, const float (&x)[8]) {
  *(float4*)(p + lane * 4) = make_float4(x[0], x[1], x[2], x[3]);
  *(float4*)(p + 256 + lane * 4) = make_float4(x[4], x[5], x[6], x[7]);
}
DEVI void st8bf(unsigned short* __restrict__ p, int lane, const float (&x)[8]) {
  *(ushort4*)(p + lane * 4) = make_ushort4(f2bf(x[0]), f2bf(x[1]), f2bf(x[2]), f2bf(x[3]));
  *(ushort4*)(p + 256 + lane * 4) = make_ushort4(f2bf(x[4]), f2bf(x[5]), f2bf(x[6]), f2bf(x[7]));
}
DEVI void norm8(float (&x)[8]) {
  float s = 0;
#pragma unroll
  for (int j = 0; j < 8; ++j) s += x[j];
  float mean = wsum(s) * (1.f / 512.f);
#pragma unroll
  for (int j = 0; j < 8; ++j) x[j] -= mean;
  float q = 0;
#pragma unroll
  for (int j = 0; j < 8; ++j) q += x[j] * x[j];
  float var = wsum(q) * (1.f / 512.f);
  float inv = rsqrtf(var + EPSf);
#pragma unroll
  for (int j = 0; j < 8; ++j) x[j] *= inv;
}

// ---- all weight conversions in ONE launch ----
DEVI void cvt8(const float* __restrict__ in, unsigned short* __restrict__ out, int i) {
  const float4* p = (const float4*)in + (size_t)i * 2;
  float4 a = p[0], b = p[1];
  *((ushort4*)out + (size_t)i * 2) = make_ushort4(f2bf(a.x), f2bf(a.y), f2bf(a.z), f2bf(a.w));
  *((ushort4*)out + (size_t)i * 2 + 1) = make_ushort4(f2bf(b.x), f2bf(b.y), f2bf(b.z), f2bf(b.w));
}
__global__ __launch_bounds__(256) void k_w2bf5(
    const float* __restrict__ s0, unsigned short* __restrict__ d0, int n0,
    const float* __restrict__ s1, unsigned short* __restrict__ d1, int n1,
    const float* __restrict__ s2, unsigned short* __restrict__ d2, int n2,
    const float* __restrict__ s3, unsigned short* __restrict__ d3, int n3,
    const float* __restrict__ s4, unsigned short* __restrict__ d4, int n4) {
  int i = blockIdx.x * 256 + threadIdx.x;
  if (i < n0) { cvt8(s0, d0, i); return; }
  i -= n0;
  if (i < n1) { cvt8(s1, d1, i); return; }
  i -= n1;
  if (i < n2) { cvt8(s2, d2, i); return; }
  i -= n2;
  if (i < n3) { cvt8(s3, d3, i); return; }
  i -= n3;
  if (i < n4) { cvt8(s4, d4, i); return; }
}

// ---- embedding + value-encoder stage 1 (+lengths on blocks 0..3) ----
__global__ __launch_bounds__(256) void k_embed(const int* __restrict__ src, const float* __restrict__ values,
    const float* __restrict__ embed, const float* __restrict__ gg, const float* __restrict__ gb,
    const float* __restrict__ vw1, const float* __restrict__ vb1,
    const unsigned char* __restrict__ mask,
    unsigned short* __restrict__ hbuf, unsigned short* __restrict__ v1bf, int* __restrict__ len) {
  __shared__ int red[4];
  int gw = (blockIdx.x * 256 + threadIdx.x) >> 6;
  int lane = threadIdx.x & 63;
  if (gw < TOK) {
    const float* er = embed + (size_t)src[gw] * DM;
    float x[8];
    ld8(er, lane, x);
    norm8(x);
    float g[8], bv[8];
    ld8(gg, lane, g); ld8(gb, lane, bv);
#pragma unroll
    for (int j = 0; j < 8; ++j) x[j] = x[j] * g[j] + bv[j];
    st8bf(hbuf + (size_t)gw * DM, lane, x);
    float val = fminf(values[gw], 512.f);
    float w1[8], b1[8];
    ld8(vw1, lane, w1); ld8(vb1, lane, b1);
    float v[8];
#pragma unroll
    for (int j = 0; j < 8; ++j) v[j] = fmaxf(val * w1[j] + b1[j], 0.f);
    st8bf(v1bf + (size_t)gw * DM, lane, v);
  }
  if (blockIdx.x < Bb) {
    int b = blockIdx.x;
    int tid = threadIdx.x;
    int cnt = 0;
    for (int t = tid; t < Ls; t += 256) cnt += mask[b * Ls + t] ? 0 : 1;
#pragma unroll
    for (int o = 32; o > 0; o >>= 1) cnt += __shfl_xor(cnt, o);
    if ((tid & 63) == 0) red[tid >> 6] = cnt;
    __syncthreads();
    if (tid == 0) len[b] = red[0] + red[1] + red[2] + red[3];
  }
}

// h = (h + LN(t2)*g+b) * (mask?0:1)   [h bf16]
__global__ __launch_bounds__(256) void k_haddv(const float* __restrict__ t2, const float* __restrict__ g,
    const float* __restrict__ bb, const unsigned char* __restrict__ mask, unsigned short* __restrict__ hbuf) {
  int gw = (blockIdx.x * 256 + threadIdx.x) >> 6;
  int lane = threadIdx.x & 63;
  if (gw >= TOK) return;
  float x[8];
  ld8(t2 + (size_t)gw * DM, lane, x);
  norm8(x);
  float gv[8], bv[8], h[8];
  ld8(g, lane, gv); ld8(bb, lane, bv);
  ld8bf(hbuf + (size_t)gw * DM, lane, h);
  float mf = mask[gw] ? 0.f : 1.f;
#pragma unroll
  for (int j = 0; j < 8; ++j) h[j] = (h[j] + x[j] * gv[j] + bv[j]) * mf;
  st8bf(hbuf + (size_t)gw * DM, lane, h);
}

// ---- LN(pre[bf16])->bf16  +  dt/ldA for BOTH directions; wdt staged in LDS ----
__global__ __launch_bounds__(256) void k_lndt(const unsigned short* __restrict__ pre, const float* __restrict__ inw,
    const float* __restrict__ dtbF, const float* __restrict__ AlogF,
    const float* __restrict__ dtbR, const float* __restrict__ AlogR,
    const int* __restrict__ len, unsigned short* __restrict__ hnbf,
    float* __restrict__ dtf, float* __restrict__ laf,
    float* __restrict__ dtr, float* __restrict__ lar) {
  __shared__ float wdts[NH * DM];
  {
    const float4* src4 = (const float4*)(inw + (size_t)NPJ * DM);
    for (int i = threadIdx.x; i < NH * DM / 4; i += 256) ((float4*)wdts)[i] = src4[i];
  }
  __syncthreads();
  int gw = (blockIdx.x * 256 + threadIdx.x) >> 6;
  int lane = threadIdx.x & 63;
  if (gw >= TOK) return;
  float x[8];
  ld8bf(pre + (size_t)gw * DM, lane, x);
  norm8(x);
  st8bf(hnbf + (size_t)gw * DM, lane, x);
  float myraw = 0.f;
#pragma unroll
  for (int hh = 0; hh < NH; ++hh) {
    float w[8];
    ld8(wdts + hh * DM, lane, w);
    float s = 0;
#pragma unroll
    for (int j = 0; j < 8; ++j) s += x[j] * w[j];
    s = wsum(s);
    if (lane == hh) myraw = s;
  }
  if (lane < NH) {
    int t = gw & (Ls - 1), b = gw >> 10;
    int ln = len[b];
    int pos = (t < ln) ? (ln - 1 - t) : t;
    size_t grev = (size_t)(b * Ls + pos);
    float rf = myraw + dtbF[lane];
    float df = rf > 20.f ? rf : log1pf(__expf(rf));
    dtf[(size_t)gw * NH + lane] = df;
    laf[(size_t)gw * NH + lane] = -__expf(AlogF[lane]) * df;
    float rr = myraw + dtbR[lane];
    float dr = rr > 20.f ? rr : log1pf(__expf(rr));
    dtr[grev * NH + lane] = dr;
    lar[grev * NH + lane] = -__expf(AlogR[lane]) * dr;
  }
}

// ---- bf16 MFMA GEMM: C[M,N] = A[M,K] @ W[N,K]^T (+bias, act) ----
template <int ACT, int OMODE>
__global__ __launch_bounds__(256) void gemm_bf(const unsigned short* __restrict__ A,
    const unsigned short* __restrict__ W, const float* __restrict__ bias,
    void* __restrict__ Cout, int M, int N, int K) {
  constexpr int BK = 64;
  __shared__ unsigned short As[128 * BK];
  __shared__ unsigned short Bs[128 * BK];
  int tid = threadIdx.x;
  int bm = blockIdx.y * 128, bn = blockIdx.x * 128;
  int wv = tid >> 6, lane = tid & 63;
  int mb = (wv >> 1) * 64, nb = (wv & 1) * 64;
  int rA = lane >> 3;
  int cswz = (lane & 7) ^ rA;
  f4v acc[4][4] = {};

  for (int k0 = 0; k0 < K; k0 += BK) {
#pragma unroll
    for (int q = 0; q < 4; ++q) {
      int ch = wv * 4 + q;
      const unsigned short* ga = A + (size_t)(bm + ch * 8 + rA) * K + k0 + cswz * 8;
      GLOAD16(ga, &As[ch * 512]);
      const unsigned short* gb = W + (size_t)(bn + ch * 8 + rA) * K + k0 + cswz * 8;
      GLOAD16(gb, &Bs[ch * 512]);
    }
    __syncthreads();
#pragma unroll
    for (int ks = 0; ks < BK; ks += 32) {
      int kb = (ks >> 3) + (lane >> 4);
      bfrag af[4], bg[4];
#pragma unroll
      for (int i = 0; i < 4; ++i) {
        int ra_ = mb + i * 16 + (lane & 15);
        af[i] = *(const bfrag*)((const char*)As + ((ra_ * 128 + kb * 16) ^ ((ra_ & 7) << 4)));
        int rb_ = nb + i * 16 + (lane & 15);
        bg[i] = *(const bfrag*)((const char*)Bs + ((rb_ * 128 + kb * 16) ^ ((rb_ & 7) << 4)));
      }
#pragma unroll
      for (int i = 0; i < 4; ++i)
#pragma unroll
        for (int j = 0; j < 4; ++j)
          acc[i][j] = __builtin_amdgcn_mfma_f32_16x16x32_bf16(af[i], bg[j], acc[i][j], 0, 0, 0);
    }
    __syncthreads();
  }

  int cb = bn + nb + (lane & 15);
  int rb = bm + mb + ((lane >> 4) << 2);
#pragma unroll
  for (int j = 0; j < 4; ++j) {
    float bv = bias ? bias[cb + j * 16] : 0.f;
#pragma unroll
    for (int i = 0; i < 4; ++i) {
#pragma unroll
      for (int r = 0; r < 4; ++r) {
        float v = acc[i][j][r] + bv;
        if (ACT == 1) v = fmaxf(v, 0.f);
        if (ACT == 2) v = v > 0.f ? v : 0.01f * v;
        size_t idx = (size_t)(rb + i * 16 + r) * N + cb + j * 16;
        if (OMODE == 0) ((float*)Cout)[idx] = v;
        else ((unsigned short*)Cout)[idx] = f2bf(v);
      }
    }
  }
}

// ---- shared B/C conv+silu, both dirs: bcbuf[dir][bt][128] (B=0..63, C=64..127) ----
__global__ __launch_bounds__(256) void k_convbc(const unsigned short* __restrict__ zx,
    const float* __restrict__ cwF, const float* __restrict__ cbF,
    const float* __restrict__ cwR, const float* __restrict__ cbR,
    const int* __restrict__ len, unsigned short* __restrict__ bcbuf) {
  int idx = blockIdx.x * 256 + threadIdx.x;
  if (idx >= 2 * TOK * 128) return;
  int col = idx & 127;
  int bt = (idx >> 7) & (TOK - 1);
  int dir = idx >> 19;
  int b = bt >> 10, t = bt & (Ls - 1);
  int ln = len[b];
  const float* cw = dir ? cwR : cwF;
  const float* cb = dir ? cbR : cbF;
  int ccd = DI + col;
  float4 w4 = *(const float4*)(cw + ccd * 4);
  float s = cb[ccd];
  float wk[4] = {w4.x, w4.y, w4.z, w4.w};
#pragma unroll
  for (int k = 0; k < 4; ++k) {
    int rl = t - 3 + k;
    if (rl >= 0) {
      int gr = dir ? (rl < ln ? ln - 1 - rl : rl) : rl;
      s += wk[k] * bf2f(zx[((size_t)(b * Ls + gr)) * NPJ + 2 * DI + col]);
    }
  }
  s = s * sigmoidf_(s);
  bcbuf[idx] = f2bf(s);
}

// ======================= fused x-conv + chunked SSD, both dirs (MFMA) =======================
// LDS tile reuse: Cb = {C -> W -> Y}, Bbs = {B -> fB^T -> G}, xT = x^T. 25 KB total.
__global__ __launch_bounds__(256) void k_chunk(const unsigned short* __restrict__ zx,
    const unsigned short* __restrict__ bcbuf,
    const float* __restrict__ cwF, const float* __restrict__ cbF,
    const float* __restrict__ cwR, const float* __restrict__ cbR,
    const float* __restrict__ dtF, const float* __restrict__ laF,
    const float* __restrict__ dtR, const float* __restrict__ laR,
    const float* __restrict__ DkF, const float* __restrict__ DkR,
    const int* __restrict__ len,
    unsigned short* __restrict__ yF, unsigned short* __restrict__ yR,
    unsigned short* __restrict__ gbuf, float* __restrict__ cumbuf) {
  __shared__ unsigned short Cb[4096], Bbs[4096], xT[4096];
  __shared__ float ldsL[64], sdt_[64], fs[64];
  int blk2 = blockIdx.x;
  int dir = blk2 >> 10;
  int blk = blk2 & 1023;
  int c = blk & 15, bh = blk >> 4, h = bh & 15, b = bh >> 4;
  int tid = threadIdx.x, wv = tid >> 6, lane = tid & 63;
  int c0 = c * CH;
  int ln = len[b];
  const float* cw = dir ? cwR : cwF;
  const float* cbias = dir ? cbR : cbF;
  const float* dtp = dir ? dtR : dtF;
  const float* ldap = dir ? laR : laF;
  float Dh = (dir ? DkR : DkF)[h];
  unsigned short* y = dir ? yR : yF;

  if (tid < 64) {
    size_t off = ((size_t)(b * Ls + c0 + tid)) * NH + h;
    float dtv = dtp[off];
    float v = ldap[off];
#pragma unroll
    for (int o = 1; o < 64; o <<= 1) {
      float n = __shfl_up(v, o);
      if (tid >= o) v += n;
    }
    ldsL[tid] = v;
    sdt_[tid] = dtv;
    cumbuf[(size_t)blk2 * 64 + tid] = __expf(v);
    float L63 = __shfl(v, 63);
    fs[tid] = __expf(L63 - v) * dtv;
  }
  __syncthreads();

  // stage B (rows) + C tiles from bcbuf (vectorized)
  {
    const unsigned short* bc = bcbuf + ((size_t)(dir * TOK + b * Ls + c0)) * 128;
    int r = tid >> 2;
    int colq = (tid & 3) * 32;
#pragma unroll
    for (int g = 0; g < 2; ++g) {
      int col = colq + g * 16;
      u16x8 v0 = *(const u16x8*)(bc + (size_t)r * 128 + col);
      u16x8 v1 = *(const u16x8*)(bc + (size_t)r * 128 + col + 8);
      if (col < 64) {
        *(u16x8*)((char*)Bbs + ((r * 128 + col * 2) ^ ((r & 7) << 4))) = v0;
        *(u16x8*)((char*)Bbs + ((r * 128 + col * 2 + 16) ^ ((r & 7) << 4))) = v1;
      } else {
        int n = col - 64;
        *(u16x8*)((char*)Cb + ((r * 128 + n * 2) ^ ((r & 7) << 4))) = v0;
        *(u16x8*)((char*)Cb + ((r * 128 + n * 2 + 16) ^ ((r & 7) << 4))) = v1;
      }
    }
  }
  // x-conv (per-head 64 channels), pack transposed xT[p][t]
  {
    int cch = tid & 63;
    int tg = (tid >> 6) * 16;
    int gcol = DI + h * 64 + cch;
    int ccd = h * 64 + cch;
    float4 w4 = *(const float4*)(cw + ccd * 4);
    float bias = cbias[ccd];
    float vv[19];
#pragma unroll
    for (int k = 0; k < 19; ++k) {
      int rl = c0 + tg - 3 + k;
      float val = 0.f;
      if (rl >= 0) {
        int gr = dir ? (rl < ln ? ln - 1 - rl : rl) : rl;
        val = bf2f(zx[((size_t)(b * Ls + gr)) * NPJ + gcol]);
      }
      vv[k] = val;
    }
    int p = cch;
#pragma unroll
    for (int hv = 0; hv < 2; ++hv) {
      u16x8 pk;
#pragma unroll
      for (int k = 0; k < 8; ++k) {
        int t = hv * 8 + k;
        float s = bias + w4.x * vv[t] + w4.y * vv[t + 1] + w4.z * vv[t + 2] + w4.w * vv[t + 3];
        pk[k] = f2bf(s * sigmoidf_(s));
      }
      *(u16x8*)((char*)xT + ((p * 128 + (tg + hv * 8) * 2) ^ ((p & 7) << 4))) = pk;
    }
  }
  __syncthreads();

  // matmul1: S[t][s] = C . B^T  (reads Cb, Bbs)
  f4v accS[4] = {};
#pragma unroll
  for (int ks = 0; ks < 64; ks += 32) {
    int kb = (ks >> 3) + (lane >> 4);
    int ra = wv * 16 + (lane & 15);
    bfrag af = *(const bfrag*)((const char*)Cb + ((ra * 128 + kb * 16) ^ ((ra & 7) << 4)));
#pragma unroll
    for (int j = 0; j < 4; ++j) {
      int rb = j * 16 + (lane & 15);
      bfrag bg = *(const bfrag*)((const char*)Bbs + ((rb * 128 + kb * 16) ^ ((rb & 7) << 4)));
      accS[j] = __builtin_amdgcn_mfma_f32_16x16x32_bf16(af, bg, accS[j], 0, 0, 0);
    }
  }
  // read BbT source values (fs-scaled) from Bbs into regs
  float vals[16];
  int nB = tid & 63, tgB = (tid >> 6) * 16;
#pragma unroll
  for (int t = 0; t < 16; ++t) {
    int s = tgB + t;
    unsigned short raw = *(const unsigned short*)((const char*)Bbs + ((s * 128 + nB * 2) ^ ((s & 7) << 4)));
    vals[t] = bf2f(raw) * fs[s];
  }
  __syncthreads();  // all reads of Cb/Bbs complete

  // overwrite: Wt -> Cb space, BbT -> Bbs space
  {
    int trow = wv * 16 + ((lane >> 4) << 2);
#pragma unroll
    for (int j = 0; j < 4; ++j) {
      int s = j * 16 + (lane & 15);
      float ds = sdt_[s], Lsv = ldsL[s];
#pragma unroll
      for (int r = 0; r < 4; ++r) {
        int tt = trow + r;
        float wval = (s <= tt) ? accS[j][r] * ds * __expf(ldsL[tt] - Lsv) : 0.f;
        *(unsigned short*)((char*)Cb + ((tt * 128 + s * 2) ^ ((tt & 7) << 4))) = f2bf(wval);
      }
    }
  }
#pragma unroll
  for (int hv = 0; hv < 2; ++hv) {
    u16x8 pk;
#pragma unroll
    for (int k = 0; k < 8; ++k) pk[k] = f2bf(vals[hv * 8 + k]);
    *(u16x8*)((char*)Bbs + ((nB * 128 + (tgB + hv * 8) * 2) ^ ((nB & 7) << 4))) = pk;
  }
  __syncthreads();

  // matmul2: Y = W @ x ; matmul3: G = (fB)^T @ x   (W in Cb, fB^T in Bbs)
  f4v accY[4] = {}, accG[4] = {};
#pragma unroll
  for (int ks = 0; ks < 64; ks += 32) {
    int kb = (ks >> 3) + (lane >> 4);
    int ra = wv * 16 + (lane & 15);
    bfrag afW = *(const bfrag*)((const char*)Cb + ((ra * 128 + kb * 16) ^ ((ra & 7) << 4)));
    bfrag afB = *(const bfrag*)((const char*)Bbs + ((ra * 128 + kb * 16) ^ ((ra & 7) << 4)));
#pragma unroll
    for (int j = 0; j < 4; ++j) {
      int rb = j * 16 + (lane & 15);
      bfrag bg = *(const bfrag*)((const char*)xT + ((rb * 128 + kb * 16) ^ ((rb & 7) << 4)));
      accY[j] = __builtin_amdgcn_mfma_f32_16x16x32_bf16(afW, bg, accY[j], 0, 0, 0);
      accG[j] = __builtin_amdgcn_mfma_f32_16x16x32_bf16(afB, bg, accG[j], 0, 0, 0);
    }
  }
  // fold D*x into Y (reads xT)
  float yout[4][4];
  int trow = wv * 16 + ((lane >> 4) << 2);
#pragma unroll
  for (int j = 0; j < 4; ++j) {
    int p = j * 16 + (lane & 15);
#pragma unroll
    for (int r = 0; r < 4; ++r) {
      int t = trow + r;
      float xval = bf2f(*(const unsigned short*)((const char*)xT + ((p * 128 + t * 2) ^ ((p & 7) << 4))));
      yout[j][r] = accY[j][r] + Dh * xval;
    }
  }
  __syncthreads();  // all LDS reads done

  // stage Y -> Cb space, G -> Bbs space (bf16, row-swizzled [t][p])
#pragma unroll
  for (int j = 0; j < 4; ++j) {
    int p = j * 16 + (lane & 15);
#pragma unroll
    for (int r = 0; r < 4; ++r) {
      int t = trow + r;
      int off = (t * 128 + p * 2) ^ ((t & 7) << 4);
      *(unsigned short*)((char*)Cb + off) = f2bf(yout[j][r]);
      *(unsigned short*)((char*)Bbs + off) = f2bf(accG[j][r]);
    }
  }
  __syncthreads();

  // coalesced global stores
  {
    int r = tid >> 2, colq = (tid & 3) * 16;
    int o0 = (r * 128 + colq * 2) ^ ((r & 7) << 4);
    int o1 = (r * 128 + colq * 2 + 16) ^ ((r & 7) << 4);
    u16x8 yv0 = *(const u16x8*)((const char*)Cb + o0);
    u16x8 yv1 = *(const u16x8*)((const char*)Cb + o1);
    unsigned short* yp = y + ((size_t)(b * Ls + c0 + r)) * DI + h * 64 + colq;
    *(u16x8*)yp = yv0;
    *(u16x8*)(yp + 8) = yv1;
    u16x8 gv0 = *(const u16x8*)((const char*)Bbs + o0);
    u16x8 gv1 = *(const u16x8*)((const char*)Bbs + o1);
    unsigned short* gp = gbuf + ((size_t)blk2 * 64 + r) * 64 + colq;
    *(u16x8*)gp = gv0;
    *(u16x8*)(gp + 8) = gv1;
  }
}

// inter-chunk recurrence, bf16 storage, fp32 accumulator, 2-deep prefetch; grid 256
__global__ __launch_bounds__(256) void k_chain(unsigned short* __restrict__ gbuf,
                                               const float* __restrict__ cumbuf) {
  int blk = blockIdx.x;          // 128 groups x 2 splits
  int grp = blk >> 1, sp = blk & 1;
  size_t base = (size_t)grp * NCH * 4096 + sp * 2048 + (size_t)threadIdx.x * 8;
  const float* cum = cumbuf + (size_t)grp * NCH * 64 + 63;
  float hv[8] = {};
  u16x8 g0 = *(const u16x8*)(gbuf + base);
  u16x8 g1 = *(const u16x8*)(gbuf + base + 4096);
  float P0 = cum[0], P1 = cum[64];
  for (int c = 0; c < NCH; ++c) {
    u16x8 g2 = {};
    float P2 = 0.f;
    if (c + 2 < NCH) {
      g2 = *(const u16x8*)(gbuf + base + (size_t)(c + 2) * 4096);
      P2 = cum[(size_t)(c + 2) * 64];
    }
    u16x8 o;
#pragma unroll
    for (int k = 0; k < 8; ++k) o[k] = f2bf(hv[k]);
    *(u16x8*)(gbuf + base + (size_t)c * 4096) = o;
#pragma unroll
    for (int k = 0; k < 8; ++k) hv[k] = fmaf(P0, hv[k], bf2f(g0[k]));
    g0 = g1; g1 = g2; P0 = P1; P1 = P2;
  }
}

// correction: Y[t][p] += exp(L[t]) * sum_n C[t][n] * hin[n][p]; grid 2*Bb*NH*15 (skips c==0)
__global__ __launch_bounds__(256) void k_corr(const unsigned short* __restrict__ bcbuf,
    const unsigned short* __restrict__ gbuf, const float* __restrict__ cumbuf,
    unsigned short* __restrict__ yF, unsigned short* __restrict__ yR) {
  __shared__ unsigned short Ct[4096], HT[4096];
  __shared__ float cdl[64];
  int bid = blockIdx.x;
  int dir = bid / (Bb * NH * 15);
  int rem = bid - dir * (Bb * NH * 15);
  int bh = rem / 15;
  int c = 1 + rem - bh * 15;
  int blk2 = dir * 1024 + bh * 16 + c;
  int h = bh & 15, b = bh >> 4;
  int tid = threadIdx.x, wv = tid >> 6, lane = tid & 63;
  int c0 = c * CH;
  unsigned short* y = dir ? yR : yF;
  {
    int r = tid >> 2;
    int colq = (tid & 3) * 16;
    const unsigned short* bc = bcbuf + ((size_t)(dir * TOK + b * Ls + c0 + r)) * 128 + 64 + colq;
    u16x8 v0 = *(const u16x8*)bc;
    u16x8 v1 = *(const u16x8*)(bc + 8);
    *(u16x8*)((char*)Ct + ((r * 128 + colq * 2) ^ ((r & 7) << 4))) = v0;
    *(u16x8*)((char*)Ct + ((r * 128 + colq * 2 + 16) ^ ((r & 7) << 4))) = v1;
  }
  {
    int n = tid >> 2, p0 = (tid & 3) * 16;
    const unsigned short* hr = gbuf + (size_t)blk2 * 4096 + (size_t)n * 64 + p0;
    u16x8 v0 = *(const u16x8*)hr;
    u16x8 v1 = *(const u16x8*)(hr + 8);
#pragma unroll
    for (int k = 0; k < 8; ++k) {
      int p = p0 + k;
      *(unsigned short*)((char*)HT + ((p * 128 + n * 2) ^ ((p & 7) << 4))) = v0[k];
      int p2 = p0 + 8 + k;
      *(unsigned short*)((char*)HT + ((p2 * 128 + n * 2) ^ ((p2 & 7) << 4))) = v1[k];
    }
  }
  if (tid < 64) cdl[tid] = cumbuf[(size_t)blk2 * 64 + tid];
  __syncthreads();

  f4v acc[4] = {};
#pragma unroll
  for (int ks = 0; ks < 64; ks += 32) {
    int kb = (ks >> 3) + (lane >> 4);
    int ra = wv * 16 + (lane & 15);
    bfrag af = *(const bfrag*)((const char*)Ct + ((ra * 128 + kb * 16) ^ ((ra & 7) << 4)));
#pragma unroll
    for (int j = 0; j < 4; ++j) {
      int rb = j * 16 + (lane & 15);
      bfrag bg = *(const bfrag*)((const char*)HT + ((rb * 128 + kb * 16) ^ ((rb & 7) << 4)));
      acc[j] = __builtin_amdgcn_mfma_f32_16x16x32_bf16(af, bg, acc[j], 0, 0, 0);
    }
  }
  __syncthreads();  // done reading Ct/HT

  // stage cdl-scaled correction into Ct space (bf16, row-swizzled [t][p])
  int trow = wv * 16 + ((lane >> 4) << 2);
#pragma unroll
  for (int j = 0; j < 4; ++j) {
    int p = j * 16 + (lane & 15);
#pragma unroll
    for (int r = 0; r < 4; ++r) {
      int t = trow + r;
      *(unsigned short*)((char*)Ct + ((t * 128 + p * 2) ^ ((t & 7) << 4))) = f2bf(cdl[t] * acc[j][r]);
    }
  }
  __syncthreads();

  // coalesced RMW
  {
    int r = tid >> 2, colq = (tid & 3) * 16;
    u16x8 c0v = *(const u16x8*)((const char*)Ct + ((r * 128 + colq * 2) ^ ((r & 7) << 4)));
    u16x8 c1v = *(const u16x8*)((const char*)Ct + ((r * 128 + colq * 2 + 16) ^ ((r & 7) << 4)));
    unsigned short* yp = y + ((size_t)(b * Ls + c0 + r)) * DI + h * 64 + colq;
    u16x8 y0 = *(const u16x8*)yp;
    u16x8 y1 = *(const u16x8*)(yp + 8);
#pragma unroll
    for (int k = 0; k < 8; ++k) {
      y0[k] = f2bf(bf2f(y0[k]) + bf2f(c0v[k]));
      y1[k] = f2bf(bf2f(y1[k]) + bf2f(c1v[k]));
    }
    *(u16x8*)yp = y0;
    *(u16x8*)(yp + 8) = y1;
  }
}
// ================================================================

// ---- both-direction gated RMSNorm: ybf[w] = 0.5*(gate_f(w) + gate_r(flip(w))) ----
__global__ __launch_bounds__(256) void k_gab(const unsigned short* __restrict__ yF,
    const unsigned short* __restrict__ yR, const unsigned short* __restrict__ zxb,
    const float* __restrict__ nwF, const float* __restrict__ nwR,
    const int* __restrict__ len, unsigned short* __restrict__ ybf) {
  int w = (blockIdx.x * 256 + threadIdx.x) >> 6;
  int lane = threadIdx.x & 63;
  if (w >= TOK) return;
  int t = w & (Ls - 1), b = w >> 10;
  int ln = len[b];
  int r = b * Ls + ((t < ln) ? (ln - 1 - t) : t);
  const unsigned short* yf = yF + (size_t)w * DI;
  const unsigned short* yr = yR + (size_t)r * DI;
  const unsigned short* zr = zxb + (size_t)w * NPJ;
  float gf[16], gr[16];
  float ssf = 0.f, ssr = 0.f;
#pragma unroll
  for (int q = 0; q < 4; ++q) {
    ushort4 yv = *(const ushort4*)(yf + lane * 4 + q * 256);
    ushort4 rv = *(const ushort4*)(yr + lane * 4 + q * 256);
    ushort4 zu = *(const ushort4*)(zr + lane * 4 + q * 256);
    float z0 = bf2f(zu.x), z1 = bf2f(zu.y), z2 = bf2f(zu.z), z3 = bf2f(zu.w);
    float s0 = z0 * sigmoidf_(z0), s1 = z1 * sigmoidf_(z1), s2 = z2 * sigmoidf_(z2), s3 = z3 * sigmoidf_(z3);
    gf[4 * q + 0] = bf2f(yv.x) * s0; gf[4 * q + 1] = bf2f(yv.y) * s1;
    gf[4 * q + 2] = bf2f(yv.z) * s2; gf[4 * q + 3] = bf2f(yv.w) * s3;
    gr[4 * q + 0] = bf2f(rv.x) * s0; gr[4 * q + 1] = bf2f(rv.y) * s1;
    gr[4 * q + 2] = bf2f(rv.z) * s2; gr[4 * q + 3] = bf2f(rv.w) * s3;
#pragma unroll
    for (int j = 0; j < 4; ++j) {
      ssf += gf[4 * q + j] * gf[4 * q + j];
      ssr += gr[4 * q + j] * gr[4 * q + j];
    }
  }
  ssf = wsum(ssf);
  ssr = wsum(ssr);
  float scf = 0.5f * rsqrtf(ssf * (1.f / (float)DI) + EPSf);
  float scr = 0.5f * rsqrtf(ssr * (1.f / (float)DI) + EPSf);
#pragma unroll
  for (int q = 0; q < 4; ++q) {
    float4 nf = *(const float4*)(nwF + lane * 4 + q * 256);
    float4 nr = *(const float4*)(nwR + lane * 4 + q * 256);
    float o0 = gf[4 * q + 0] * scf * nf.x + gr[4 * q + 0] * scr * nr.x;
    float o1 = gf[4 * q + 1] * scf * nf.y + gr[4 * q + 1] * scr * nr.y;
    float o2 = gf[4 * q + 2] * scf * nf.z + gr[4 * q + 2] * scr * nr.z;
    float o3 = gf[4 * q + 3] * scf * nf.w + gr[4 * q + 3] * scr * nr.w;
    *(ushort4*)(ybf + (size_t)w * DI + lane * 4 + q * 256) =
        make_ushort4(f2bf(o0), f2bf(o1), f2bf(o2), f2bf(o3));
  }
}

// ---- hnbf = LN(src[bf16]) bf16 (heads input); rows t==0 also -> cell out (fp32) + cc0 ----
__global__ __launch_bounds__(256) void k_hl2(const unsigned short* __restrict__ src,
    unsigned short* __restrict__ dstbf, float* __restrict__ cellout, float* __restrict__ cc0) {
  int gw = (blockIdx.x * 256 + threadIdx.x) >> 6;
  int lane = threadIdx.x & 63;
  if (gw >= TOK) return;
  float x[8];
  ld8bf(src + (size_t)gw * DM, lane, x);
  norm8(x);
  st8bf(dstbf + (size_t)gw * DM, lane, x);
  if ((gw & (Ls - 1)) == 0) {
    int b = gw >> 10;
    st8(cellout + (size_t)b * DM, lane, x);
    st8(cc0 + (size_t)b * DM, lane, x);
  }
}

// ---- mlm head (bf16 input) ----
__global__ __launch_bounds__(256) void k_mlm(const unsigned short* __restrict__ e2,
                                             const float* __restrict__ w3,
                                             const float* __restrict__ b3, float* __restrict__ out) {
  int gw = (blockIdx.x * 256 + threadIdx.x) >> 6;
  int lane = threadIdx.x & 63;
  if (gw >= TOK) return;
  float x[8], w[8];
  ld8bf(e2 + (size_t)gw * DM, lane, x);
  ld8(w3, lane, w);
  float s = 0;
#pragma unroll
  for (int j = 0; j < 8; ++j) s += x[j] * w[j];
  s = wsum(s);
  if (lane == 0) out[gw] = s + b3[0];
}

// ---- classifier matvec (wave-per-output; optional LN+affine on input) ----
__global__ __launch_bounds__(256) void k_clsmv(const float* __restrict__ xin, size_t xstride,
    const float* __restrict__ g, const float* __restrict__ bb, int doLN,
    const float* __restrict__ W, const float* __restrict__ bias, int doRelu,
    float* __restrict__ out, int nout) {
  int b = blockIdx.y;
  int j = blockIdx.x * 4 + (threadIdx.x >> 6);
  int lane = threadIdx.x & 63;
  if (j >= nout) return;
  float x[8];
  ld8(xin + (size_t)b * xstride, lane, x);
  if (doLN) {
    norm8(x);
    float gv[8], bv[8];
    ld8(g, lane, gv); ld8(bb, lane, bv);
#pragma unroll
    for (int k = 0; k < 8; ++k) x[k] = x[k] * gv[k] + bv[k];
  }
  float w[8];
  ld8(W + (size_t)j * DM, lane, w);
  float s = 0;
#pragma unroll
  for (int k = 0; k < 8; ++k) s += x[k] * w[k];
  s = wsum(s);
  if (lane == 0) {
    float v = s + bias[j];
    if (doRelu) v = fmaxf(v, 0.f);
    out[(size_t)b * nout + j] = v;
  }
}

// ---- workspace layout (floats) ----
constexpr size_t F_T2  = 0;
constexpr size_t F_DTF = F_T2 + (size_t)TOK * DM;
constexpr size_t F_LAF = F_DTF + (size_t)TOK * NH;
constexpr size_t F_DTR = F_LAF + (size_t)TOK * NH;
constexpr size_t F_LAR = F_DTR + (size_t)TOK * NH;
constexpr size_t F_CUM = F_LAR + (size_t)TOK * NH;
constexpr size_t F_CC0 = F_CUM + (size_t)2 * Bb * NH * NCH * 64;
constexpr size_t F_CC1 = F_CC0 + Bb * DM;
constexpr size_t F_CC2 = F_CC1 + Bb * DM;
constexpr size_t F_LEN = F_CC2 + Bb * DM;
constexpr size_t F_END = F_LEN + 16;
// bf16 regions (ushort offsets)
constexpr size_t U0     = F_END * 2;
constexpr size_t UW_IN  = U0;
constexpr size_t UW_OUT = UW_IN + (size_t)2 * DIP * DM;
constexpr size_t UW_VE  = UW_OUT + (size_t)2 * DM * DI;
constexpr size_t UW_E1  = UW_VE + (size_t)DM * DM;
constexpr size_t UW_E2  = UW_E1 + (size_t)DM * DM;
constexpr size_t U_BFA  = UW_E2 + (size_t)DM * DM;   // v1 / e1-bf16
constexpr size_t U_HNBF = U_BFA + (size_t)TOK * DM;
constexpr size_t U_YBF  = U_HNBF + (size_t)TOK * DM;
constexpr size_t U_ZX   = U_YBF + (size_t)TOK * DI;   // bf16 zx (TOK*NPJ)
constexpr size_t U_YF   = U_ZX + (size_t)TOK * NPJ;   // bf16 y fwd
constexpr size_t U_YR   = U_YF + (size_t)TOK * DI;    // bf16 y rev
constexpr size_t U_G    = U_YR + (size_t)TOK * DI;    // bf16 G/hin (2*1024*4096)
constexpr size_t U_H    = U_G + (size_t)2 * 1024 * 4096;  // bf16 residual h
constexpr size_t U_ON   = U_H + (size_t)TOK * DM;         // bf16 residual onew

extern "C" void kernel_launch(void* const* d_in, const int* in_sizes, int n_in,
                              void* d_out, int out_size, void* d_ws, size_t ws_size,
                              hipStream_t stream) {
  const int* src = (const int*)d_in[0];
  const float* values = (const float*)d_in[1];
  const unsigned char* mask = (const unsigned char*)d_in[2];
  const float* embed = (const float*)d_in[3];
  const float* ge_g = (const float*)d_in[4];
  const float* ge_b = (const float*)d_in[5];
  const float* ve_w1 = (const float*)d_in[6];
  const float* ve_b1 = (const float*)d_in[7];
  const float* ve_w2 = (const float*)d_in[8];
  const float* ve_b2 = (const float*)d_in[9];
  const float* ve_g = (const float*)d_in[10];
  const float* ve_bb = (const float*)d_in[11];
  const float* in_w = (const float*)d_in[12];
  const float* conv_w_f = (const float*)d_in[13];
  const float* conv_b_f = (const float*)d_in[14];
  const float* A_f = (const float*)d_in[15];
  const float* dtb_f = (const float*)d_in[16];
  const float* D_f = (const float*)d_in[17];
  const float* nw_f = (const float*)d_in[18];
  const float* conv_w_r = (const float*)d_in[19];
  const float* conv_b_r = (const float*)d_in[20];
  const float* A_r = (const float*)d_in[21];
  const float* dtb_r = (const float*)d_in[22];
  const float* D_r = (const float*)d_in[23];
  const float* nw_r = (const float*)d_in[24];
  const float* out_w = (const float*)d_in[25];
  const float* expr_w1 = (const float*)d_in[26];
  const float* expr_b1 = (const float*)d_in[27];
  const float* expr_w2 = (const float*)d_in[28];
  const float* expr_b2 = (const float*)d_in[29];
  const float* expr_w3 = (const float*)d_in[30];
  const float* expr_b3 = (const float*)d_in[31];
  const float* cls_w1 = (const float*)d_in[32];
  const float* cls_b1 = (const float*)d_in[33];
  const float* cls_g1 = (const float*)d_in[34];
  const float* cls_bb1 = (const float*)d_in[35];
  const float* cls_w2 = (const float*)d_in[36];
  const float* cls_b2 = (const float*)d_in[37];
  const float* cls_g2 = (const float*)d_in[38];
  const float* cls_bb2 = (const float*)d_in[39];
  const float* cls_wo = (const float*)d_in[40];
  const float* cls_bo = (const float*)d_in[41];

  float* ws = (float*)d_ws;
  unsigned short* wsu = (unsigned short*)d_ws;
  float* t2 = ws + F_T2;
  float* dtf = ws + F_DTF;
  float* laf = ws + F_LAF;
  float* dtr = ws + F_DTR;
  float* lar = ws + F_LAR;
  float* cumb = ws + F_CUM;
  float* cc0 = ws + F_CC0;
  float* cc1 = ws + F_CC1;
  float* cc2 = ws + F_CC2;
  int* len = (int*)(ws + F_LEN);
  unsigned short* w_in = wsu + UW_IN;
  unsigned short* w_out = wsu + UW_OUT;
  unsigned short* w_ve = wsu + UW_VE;
  unsigned short* w_e1 = wsu + UW_E1;
  unsigned short* w_e2 = wsu + UW_E2;
  unsigned short* bfa = wsu + U_BFA;
  unsigned short* hnbf = wsu + U_HNBF;
  unsigned short* ybf = wsu + U_YBF;
  unsigned short* zxb = wsu + U_ZX;
  unsigned short* yFb = wsu + U_YF;
  unsigned short* yRb = wsu + U_YR;
  unsigned short* gbuf = wsu + U_G;
  unsigned short* hb = wsu + U_H;
  unsigned short* onewb = wsu + U_ON;
  unsigned short* bcbuf = ybf;      // reuse: bcbuf (2*TOK*128) lives in ybf until gab writes it
  unsigned short* e2b = zxb;        // reuse after layers
  float* out = (float*)d_out;

  // ---- weight conversions (single launch) ----
  {
    int n0 = 2 * DIP * DM / 8, n1 = 2 * DM * DI / 8, n2 = DM * DM / 8, n3 = n2, n4 = n2;
    int tot = n0 + n1 + n2 + n3 + n4;
    k_w2bf5<<<(tot + 255) / 256, 256, 0, stream>>>(in_w, w_in, n0, out_w, w_out, n1,
                                                   ve_w2, w_ve, n2, expr_w1, w_e1, n3,
                                                   expr_w2, w_e2, n4);
  }

  // ---- embedding + value encoder (+lengths) ----
  k_embed<<<TOK / 4, 256, 0, stream>>>(src, values, embed, ge_g, ge_b, ve_w1, ve_b1, mask,
                                       hb, bfa, len);
  gemm_bf<0, 0><<<dim3(DM / 128, TOK / 128), 256, 0, stream>>>(bfa, w_ve, ve_b2, t2, TOK, DM, DM);
  k_haddv<<<TOK / 4, 256, 0, stream>>>(t2, ve_g, ve_bb, mask, hb);

  // ---- layers ----
  for (int i = 0; i < 2; ++i) {
    const float* inw = in_w + (size_t)i * DIP * DM;
    unsigned short* inwb = w_in + (size_t)i * DIP * DM;
    unsigned short* outwb = w_out + (size_t)i * DM * DI;
    const float* cwF = conv_w_f + (size_t)i * CDIM * 4;
    const float* cbF = conv_b_f + (size_t)i * CDIM;
    const float* cwR = conv_w_r + (size_t)i * CDIM * 4;
    const float* cbR = conv_b_r + (size_t)i * CDIM;
    const unsigned short* pre = (i == 0) ? hb : onewb;
    k_lndt<<<TOK / 4, 256, 0, stream>>>(pre, inw, dtb_f + i * NH, A_f + i * NH,
                                        dtb_r + i * NH, A_r + i * NH, len, hnbf,
                                        dtf, laf, dtr, lar);
    gemm_bf<0, 1><<<dim3(NPJ / 128, TOK / 128), 256, 0, stream>>>(hnbf, inwb, nullptr, zxb, TOK, NPJ, DM);
    k_convbc<<<(2 * TOK * 128) / 256, 256, 0, stream>>>(zxb, cwF, cbF, cwR, cbR, len, bcbuf);
    k_chunk<<<2 * Bb * NH * NCH, 256, 0, stream>>>(zxb, bcbuf, cwF, cbF, cwR, cbR,
        dtf, laf, dtr, lar, D_f + i * NH, D_r + i * NH, len, yFb, yRb, gbuf, cumb);
    k_chain<<<2 * 2 * Bb * NH, 256, 0, stream>>>(gbuf, cumb);
    k_corr<<<2 * Bb * NH * 15, 256, 0, stream>>>(bcbuf, gbuf, cumb, yFb, yRb);
    k_gab<<<TOK / 4, 256, 0, stream>>>(yFb, yRb, zxb, nw_f + (size_t)i * DI, nw_r + (size_t)i * DI,
                                       len, ybf);
    gemm_bf<0, 1><<<dim3(DM / 128, TOK / 128), 256, 0, stream>>>(ybf, outwb, nullptr, onewb, TOK, DM, DI);
  }

  // ---- heads ----
  k_hl2<<<TOK / 4, 256, 0, stream>>>(onewb, hnbf, out + TOK, cc0);
  gemm_bf<2, 1><<<dim3(DM / 128, TOK / 128), 256, 0, stream>>>(hnbf, w_e1, expr_b1, bfa, TOK, DM, DM);
  gemm_bf<2, 1><<<dim3(DM / 128, TOK / 128), 256, 0, stream>>>(bfa, w_e2, expr_b2, e2b, TOK, DM, DM);
  k_mlm<<<TOK / 4, 256, 0, stream>>>(e2b, expr_w3, expr_b3, out);
  k_clsmv<<<dim3(128, Bb), 256, 0, stream>>>(cc0, DM, nullptr, nullptr, 0,
                                             cls_w1, cls_b1, 1, cc1, DM);
  k_clsmv<<<dim3(128, Bb), 256, 0, stream>>>(cc1, DM, cls_g1, cls_bb1, 1,
                                             cls_w2, cls_b2, 1, cc2, DM);
  k_clsmv<<<dim3(41, Bb), 256, 0, stream>>>(cc2, DM, cls_g2, cls_bb2, 1,
                                            cls_wo, cls_bo, 0, out + TOK + Bb * DM, 164);
}

// Round 12
// 304.267 us; speedup vs baseline: 1.0309x; 1.0309x over previous
//
#include <hip/hip_runtime.h>
#include <hip/hip_bf16.h>
#include <math.h>

// ---- model constants ----
constexpr int Bb = 4, Ls = 1024, DM = 512, DI = 1024, NH = 16, HD = 64, DS = 64;
constexpr int CDIM = DI + 2 * DS;          // 1152
constexpr int DIP  = 2 * DI + 2 * DS + NH; // 2192
constexpr int NPJ  = 2 * DI + 2 * DS;      // 2176 = 17*128
constexpr float EPSf = 1e-5f;
constexpr int TOK = Bb * Ls;               // 4096
constexpr int CH = 64, NCH = Ls / CH;      // 16 chunks of 64

#define DEVI __device__ __forceinline__

using bfrag = __attribute__((ext_vector_type(8))) short;
using f4v   = __attribute__((ext_vector_type(4))) float;
using u16x8 = __attribute__((ext_vector_type(8))) unsigned short;

#define GLOAD16(gp, lp)                                                              \
  __builtin_amdgcn_global_load_lds((__attribute__((address_space(1))) void*)(gp),   \
                                   (__attribute__((address_space(3))) void*)(lp),   \
                                   16, 0, 0)

DEVI float wsum(float v) {
#pragma unroll
  for (int o = 32; o > 0; o >>= 1) v += __shfl_xor(v, o);
  return v;
}
DEVI float sigmoidf_(float x) { return 1.f / (1.f + __expf(-x)); }
DEVI unsigned short f2bf(float x) {
  union { float f; unsigned u; } c{x};
  unsigned u = c.u;
  u += 0x7fffu + ((u >> 16) & 1u);
  return (unsigned short)(u >> 16);
}
DEVI float bf2f(unsigned short u) {
  union { unsigned u; float f; } c{(unsigned)u << 16};
  return c.f;
}

DEVI void ld8(const float* __restrict__ p, int lane, float (&x)[8]) {
  float4 a = *(const float4*)(p + lane * 4);
  float4 b = *(const float4*)(p + 256 + lane * 4);
  x[0] = a.x; x[1] = a.y; x[2] = a.z; x[3] = a.w;
  x[4] = b.x; x[5] = b.y; x[6] = b.z; x[7] = b.w;
}
DEVI void ld8bf(const unsigned short* __restrict__ p, int lane, float (&x)[8]) {
  ushort4 a = *(const ushort4*)(p + lane * 4);
  ushort4 b = *(const ushort4*)(p + 256 + lane * 4);
  x[0] = bf2f(a.x); x[1] = bf2f(a.y); x[2] = bf2f(a.z); x[3] = bf2f(a.w);
  x[4] = bf2f(b.x); x[5] = bf2f(b.y); x[6] = bf2f(b.z); x[7] = bf2f(b.w);
}
DEVI void st8(float* __restrict__ p, int lane, const float (&x)[8]) {
  *(float4*)(p + lane * 4) = make_float4(x[0], x[1], x[2], x[3]);
  *(float4*)(p + 256 + lane * 4) = make_float4(x[4], x[5], x[6], x[7]);
}
DEVI void st8bf(unsigned short* __restrict__ p, int lane, const float (&x)[8]) {
  *(ushort4*)(p + lane * 4) = make_ushort4(f2bf(x[0]), f2bf(x[1]), f2bf(x[2]), f2bf(x[3]));
  *(ushort4*)(p + 256 + lane * 4) = make_ushort4(f2bf(x[4]), f2bf(x[5]), f2bf(x[6]), f2bf(x[7]));
}
DEVI void norm8(float (&x)[8]) {
  float s = 0;
#pragma unroll
  for (int j = 0; j < 8; ++j) s += x[j];
  float mean = wsum(s) * (1.f / 512.f);
#pragma unroll
  for (int j = 0; j < 8; ++j) x[j] -= mean;
  float q = 0;
#pragma unroll
  for (int j = 0; j < 8; ++j) q += x[j] * x[j];
  float var = wsum(q) * (1.f / 512.f);
  float inv = rsqrtf(var + EPSf);
#pragma unroll
  for (int j = 0; j < 8; ++j) x[j] *= inv;
}

// ---- all weight conversions in ONE launch ----
DEVI void cvt8(const float* __restrict__ in, unsigned short* __restrict__ out, int i) {
  const float4* p = (const float4*)in + (size_t)i * 2;
  float4 a = p[0], b = p[1];
  *((ushort4*)out + (size_t)i * 2) = make_ushort4(f2bf(a.x), f2bf(a.y), f2bf(a.z), f2bf(a.w));
  *((ushort4*)out + (size_t)i * 2 + 1) = make_ushort4(f2bf(b.x), f2bf(b.y), f2bf(b.z), f2bf(b.w));
}
__global__ __launch_bounds__(256) void k_w2bf5(
    const float* __restrict__ s0, unsigned short* __restrict__ d0, int n0,
    const float* __restrict__ s1, unsigned short* __restrict__ d1, int n1,
    const float* __restrict__ s2, unsigned short* __restrict__ d2, int n2,
    const float* __restrict__ s3, unsigned short* __restrict__ d3, int n3,
    const float* __restrict__ s4, unsigned short* __restrict__ d4, int n4) {
  int i = blockIdx.x * 256 + threadIdx.x;
  if (i < n0) { cvt8(s0, d0, i); return; }
  i -= n0;
  if (i < n1) { cvt8(s1, d1, i); return; }
  i -= n1;
  if (i < n2) { cvt8(s2, d2, i); return; }
  i -= n2;
  if (i < n3) { cvt8(s3, d3, i); return; }
  i -= n3;
  if (i < n4) { cvt8(s4, d4, i); return; }
}

// ---- embedding + value-encoder stage 1 ----
__global__ __launch_bounds__(256) void k_embed(const int* __restrict__ src, const float* __restrict__ values,
    const float* __restrict__ embed, const float* __restrict__ gg, const float* __restrict__ gb,
    const float* __restrict__ vw1, const float* __restrict__ vb1,
    float* __restrict__ hbuf, unsigned short* __restrict__ v1bf) {
  int gw = (blockIdx.x * 256 + threadIdx.x) >> 6;
  int lane = threadIdx.x & 63;
  if (gw >= TOK) return;
  const float* er = embed + (size_t)src[gw] * DM;
  float x[8];
  ld8(er, lane, x);
  norm8(x);
  float g[8], bv[8];
  ld8(gg, lane, g); ld8(gb, lane, bv);
#pragma unroll
  for (int j = 0; j < 8; ++j) x[j] = x[j] * g[j] + bv[j];
  st8(hbuf + (size_t)gw * DM, lane, x);
  float val = fminf(values[gw], 512.f);
  float w1[8], b1[8];
  ld8(vw1, lane, w1); ld8(vb1, lane, b1);
  float v[8];
#pragma unroll
  for (int j = 0; j < 8; ++j) v[j] = fmaxf(val * w1[j] + b1[j], 0.f);
  st8bf(v1bf + (size_t)gw * DM, lane, v);
}

// h = (h + LN(t2)*g+b) * (mask?0:1)
__global__ __launch_bounds__(256) void k_haddv(const float* __restrict__ t2, const float* __restrict__ g,
    const float* __restrict__ bb, const unsigned char* __restrict__ mask, float* __restrict__ hbuf) {
  int gw = (blockIdx.x * 256 + threadIdx.x) >> 6;
  int lane = threadIdx.x & 63;
  if (gw >= TOK) return;
  float x[8];
  ld8(t2 + (size_t)gw * DM, lane, x);
  norm8(x);
  float gv[8], bv[8], h[8];
  ld8(g, lane, gv); ld8(bb, lane, bv);
  ld8(hbuf + (size_t)gw * DM, lane, h);
  float mf = mask[gw] ? 0.f : 1.f;
#pragma unroll
  for (int j = 0; j < 8; ++j) h[j] = (h[j] + x[j] * gv[j] + bv[j]) * mf;
  st8(hbuf + (size_t)gw * DM, lane, h);
}

// ---- LN(pre)->bf16  +  dt/ldA for BOTH directions; wdt staged in LDS ----
__global__ __launch_bounds__(256) void k_lndt(const float* __restrict__ pre, const float* __restrict__ inw,
    const float* __restrict__ dtbF, const float* __restrict__ AlogF,
    const float* __restrict__ dtbR, const float* __restrict__ AlogR,
    const int* __restrict__ len, unsigned short* __restrict__ hnbf,
    float* __restrict__ dtf, float* __restrict__ laf,
    float* __restrict__ dtr, float* __restrict__ lar) {
  __shared__ float wdts[NH * DM];
  {
    const float4* src4 = (const float4*)(inw + (size_t)NPJ * DM);
    for (int i = threadIdx.x; i < NH * DM / 4; i += 256) ((float4*)wdts)[i] = src4[i];
  }
  __syncthreads();
  int gw = (blockIdx.x * 256 + threadIdx.x) >> 6;
  int lane = threadIdx.x & 63;
  if (gw >= TOK) return;
  float x[8];
  ld8(pre + (size_t)gw * DM, lane, x);
  norm8(x);
  st8bf(hnbf + (size_t)gw * DM, lane, x);
  float myraw = 0.f;
#pragma unroll
  for (int hh = 0; hh < NH; ++hh) {
    float w[8];
    ld8(wdts + hh * DM, lane, w);
    float s = 0;
#pragma unroll
    for (int j = 0; j < 8; ++j) s += x[j] * w[j];
    s = wsum(s);
    if (lane == hh) myraw = s;
  }
  if (lane < NH) {
    int t = gw & (Ls - 1), b = gw >> 10;
    int ln = len[b];
    int pos = (t < ln) ? (ln - 1 - t) : t;
    size_t grev = (size_t)(b * Ls + pos);
    float rf = myraw + dtbF[lane];
    float df = rf > 20.f ? rf : log1pf(__expf(rf));
    dtf[(size_t)gw * NH + lane] = df;
    laf[(size_t)gw * NH + lane] = -__expf(AlogF[lane]) * df;
    float rr = myraw + dtbR[lane];
    float dr = rr > 20.f ? rr : log1pf(__expf(rr));
    dtr[grev * NH + lane] = dr;
    lar[grev * NH + lane] = -__expf(AlogR[lane]) * dr;
  }
}

// ---- bf16 MFMA GEMM: C[M,N] = A[M,K] @ W[N,K]^T (+bias, act) ----
template <int ACT, int OMODE>
__global__ __launch_bounds__(256) void gemm_bf(const unsigned short* __restrict__ A,
    const unsigned short* __restrict__ W, const float* __restrict__ bias,
    void* __restrict__ Cout, int M, int N, int K) {
  constexpr int BK = 64;
  __shared__ unsigned short As[128 * BK];
  __shared__ unsigned short Bs[128 * BK];
  int tid = threadIdx.x;
  int bm = blockIdx.y * 128, bn = blockIdx.x * 128;
  int wv = tid >> 6, lane = tid & 63;
  int mb = (wv >> 1) * 64, nb = (wv & 1) * 64;
  int rA = lane >> 3;
  int cswz = (lane & 7) ^ rA;
  f4v acc[4][4] = {};

  for (int k0 = 0; k0 < K; k0 += BK) {
#pragma unroll
    for (int q = 0; q < 4; ++q) {
      int ch = wv * 4 + q;
      const unsigned short* ga = A + (size_t)(bm + ch * 8 + rA) * K + k0 + cswz * 8;
      GLOAD16(ga, &As[ch * 512]);
      const unsigned short* gb = W + (size_t)(bn + ch * 8 + rA) * K + k0 + cswz * 8;
      GLOAD16(gb, &Bs[ch * 512]);
    }
    __syncthreads();
#pragma unroll
    for (int ks = 0; ks < BK; ks += 32) {
      int kb = (ks >> 3) + (lane >> 4);
      bfrag af[4], bg[4];
#pragma unroll
      for (int i = 0; i < 4; ++i) {
        int ra_ = mb + i * 16 + (lane & 15);
        af[i] = *(const bfrag*)((const char*)As + ((ra_ * 128 + kb * 16) ^ ((ra_ & 7) << 4)));
        int rb_ = nb + i * 16 + (lane & 15);
        bg[i] = *(const bfrag*)((const char*)Bs + ((rb_ * 128 + kb * 16) ^ ((rb_ & 7) << 4)));
      }
#pragma unroll
      for (int i = 0; i < 4; ++i)
#pragma unroll
        for (int j = 0; j < 4; ++j)
          acc[i][j] = __builtin_amdgcn_mfma_f32_16x16x32_bf16(af[i], bg[j], acc[i][j], 0, 0, 0);
    }
    __syncthreads();
  }

  int cb = bn + nb + (lane & 15);
  int rb = bm + mb + ((lane >> 4) << 2);
#pragma unroll
  for (int j = 0; j < 4; ++j) {
    float bv = bias ? bias[cb + j * 16] : 0.f;
#pragma unroll
    for (int i = 0; i < 4; ++i) {
#pragma unroll
      for (int r = 0; r < 4; ++r) {
        float v = acc[i][j][r] + bv;
        if (ACT == 1) v = fmaxf(v, 0.f);
        if (ACT == 2) v = v > 0.f ? v : 0.01f * v;
        size_t idx = (size_t)(rb + i * 16 + r) * N + cb + j * 16;
        if (OMODE == 0) ((float*)Cout)[idx] = v;
        else ((unsigned short*)Cout)[idx] = f2bf(v);
      }
    }
  }
}

// ---- shared B/C conv+silu, both dirs: bcbuf[dir][bt][128] (B=0..63, C=64..127) ----
__global__ __launch_bounds__(256) void k_convbc(const unsigned short* __restrict__ zx,
    const float* __restrict__ cwF, const float* __restrict__ cbF,
    const float* __restrict__ cwR, const float* __restrict__ cbR,
    const int* __restrict__ len, unsigned short* __restrict__ bcbuf) {
  int idx = blockIdx.x * 256 + threadIdx.x;
  if (idx >= 2 * TOK * 128) return;
  int col = idx & 127;
  int bt = (idx >> 7) & (TOK - 1);
  int dir = idx >> 19;
  int b = bt >> 10, t = bt & (Ls - 1);
  int ln = len[b];
  const float* cw = dir ? cwR : cwF;
  const float* cb = dir ? cbR : cbF;
  int ccd = DI + col;
  float4 w4 = *(const float4*)(cw + ccd * 4);
  float s = cb[ccd];
  float wk[4] = {w4.x, w4.y, w4.z, w4.w};
#pragma unroll
  for (int k = 0; k < 4; ++k) {
    int rl = t - 3 + k;
    if (rl >= 0) {
      int gr = dir ? (rl < ln ? ln - 1 - rl : rl) : rl;
      s += wk[k] * bf2f(zx[((size_t)(b * Ls + gr)) * NPJ + 2 * DI + col]);
    }
  }
  s = s * sigmoidf_(s);
  bcbuf[idx] = f2bf(s);
}

// ======================= fused x-conv + chunked SSD, both dirs (MFMA) =======================
// LDS tile reuse: Cb = {C -> W -> Y}, Bbs = {B -> fB^T -> G}, xT = x^T. 25 KB total.
__global__ __launch_bounds__(256) void k_chunk(const unsigned short* __restrict__ zx,
    const unsigned short* __restrict__ bcbuf,
    const float* __restrict__ cwF, const float* __restrict__ cbF,
    const float* __restrict__ cwR, const float* __restrict__ cbR,
    const float* __restrict__ dtF, const float* __restrict__ laF,
    const float* __restrict__ dtR, const float* __restrict__ laR,
    const float* __restrict__ DkF, const float* __restrict__ DkR,
    const int* __restrict__ len,
    unsigned short* __restrict__ yF, unsigned short* __restrict__ yR,
    unsigned short* __restrict__ gbuf, float* __restrict__ cumbuf) {
  __shared__ unsigned short Cb[4096], Bbs[4096], xT[4096];
  __shared__ float ldsL[64], sdt_[64], fs[64];
  int blk2 = blockIdx.x;
  int dir = blk2 >> 10;
  int blk = blk2 & 1023;
  int c = blk & 15, bh = blk >> 4, h = bh & 15, b = bh >> 4;
  int tid = threadIdx.x, wv = tid >> 6, lane = tid & 63;
  int c0 = c * CH;
  int ln = len[b];
  const float* cw = dir ? cwR : cwF;
  const float* cbias = dir ? cbR : cbF;
  const float* dtp = dir ? dtR : dtF;
  const float* ldap = dir ? laR : laF;
  float Dh = (dir ? DkR : DkF)[h];
  unsigned short* y = dir ? yR : yF;

  if (tid < 64) {
    size_t off = ((size_t)(b * Ls + c0 + tid)) * NH + h;
    float dtv = dtp[off];
    float v = ldap[off];
#pragma unroll
    for (int o = 1; o < 64; o <<= 1) {
      float n = __shfl_up(v, o);
      if (tid >= o) v += n;
    }
    ldsL[tid] = v;
    sdt_[tid] = dtv;
    cumbuf[(size_t)blk2 * 64 + tid] = __expf(v);
    float L63 = __shfl(v, 63);
    fs[tid] = __expf(L63 - v) * dtv;
  }
  __syncthreads();

  // stage B (rows) + C tiles from bcbuf (vectorized)
  {
    const unsigned short* bc = bcbuf + ((size_t)(dir * TOK + b * Ls + c0)) * 128;
    int r = tid >> 2;
    int colq = (tid & 3) * 32;
#pragma unroll
    for (int g = 0; g < 2; ++g) {
      int col = colq + g * 16;
      u16x8 v0 = *(const u16x8*)(bc + (size_t)r * 128 + col);
      u16x8 v1 = *(const u16x8*)(bc + (size_t)r * 128 + col + 8);
      if (col < 64) {
        *(u16x8*)((char*)Bbs + ((r * 128 + col * 2) ^ ((r & 7) << 4))) = v0;
        *(u16x8*)((char*)Bbs + ((r * 128 + col * 2 + 16) ^ ((r & 7) << 4))) = v1;
      } else {
        int n = col - 64;
        *(u16x8*)((char*)Cb + ((r * 128 + n * 2) ^ ((r & 7) << 4))) = v0;
        *(u16x8*)((char*)Cb + ((r * 128 + n * 2 + 16) ^ ((r & 7) << 4))) = v1;
      }
    }
  }
  // x-conv (per-head 64 channels), pack transposed xT[p][t]
  {
    int cch = tid & 63;
    int tg = (tid >> 6) * 16;
    int gcol = DI + h * 64 + cch;
    int ccd = h * 64 + cch;
    float4 w4 = *(const float4*)(cw + ccd * 4);
    float bias = cbias[ccd];
    float vv[19];
#pragma unroll
    for (int k = 0; k < 19; ++k) {
      int rl = c0 + tg - 3 + k;
      float val = 0.f;
      if (rl >= 0) {
        int gr = dir ? (rl < ln ? ln - 1 - rl : rl) : rl;
        val = bf2f(zx[((size_t)(b * Ls + gr)) * NPJ + gcol]);
      }
      vv[k] = val;
    }
    int p = cch;
#pragma unroll
    for (int hv = 0; hv < 2; ++hv) {
      u16x8 pk;
#pragma unroll
      for (int k = 0; k < 8; ++k) {
        int t = hv * 8 + k;
        float s = bias + w4.x * vv[t] + w4.y * vv[t + 1] + w4.z * vv[t + 2] + w4.w * vv[t + 3];
        pk[k] = f2bf(s * sigmoidf_(s));
      }
      *(u16x8*)((char*)xT + ((p * 128 + (tg + hv * 8) * 2) ^ ((p & 7) << 4))) = pk;
    }
  }
  __syncthreads();

  // matmul1: S[t][s] = C . B^T  (reads Cb, Bbs)
  f4v accS[4] = {};
#pragma unroll
  for (int ks = 0; ks < 64; ks += 32) {
    int kb = (ks >> 3) + (lane >> 4);
    int ra = wv * 16 + (lane & 15);
    bfrag af = *(const bfrag*)((const char*)Cb + ((ra * 128 + kb * 16) ^ ((ra & 7) << 4)));
#pragma unroll
    for (int j = 0; j < 4; ++j) {
      int rb = j * 16 + (lane & 15);
      bfrag bg = *(const bfrag*)((const char*)Bbs + ((rb * 128 + kb * 16) ^ ((rb & 7) << 4)));
      accS[j] = __builtin_amdgcn_mfma_f32_16x16x32_bf16(af, bg, accS[j], 0, 0, 0);
    }
  }
  // read BbT source values (fs-scaled) from Bbs into regs
  float vals[16];
  int nB = tid & 63, tgB = (tid >> 6) * 16;
#pragma unroll
  for (int t = 0; t < 16; ++t) {
    int s = tgB + t;
    unsigned short raw = *(const unsigned short*)((const char*)Bbs + ((s * 128 + nB * 2) ^ ((s & 7) << 4)));
    vals[t] = bf2f(raw) * fs[s];
  }
  __syncthreads();  // all reads of Cb/Bbs complete

  // overwrite: Wt -> Cb space, BbT -> Bbs space
  {
    int trow = wv * 16 + ((lane >> 4) << 2);
#pragma unroll
    for (int j = 0; j < 4; ++j) {
      int s = j * 16 + (lane & 15);
      float ds = sdt_[s], Lsv = ldsL[s];
#pragma unroll
      for (int r = 0; r < 4; ++r) {
        int tt = trow + r;
        float wval = (s <= tt) ? accS[j][r] * ds * __expf(ldsL[tt] - Lsv) : 0.f;
        *(unsigned short*)((char*)Cb + ((tt * 128 + s * 2) ^ ((tt & 7) << 4))) = f2bf(wval);
      }
    }
  }
#pragma unroll
  for (int hv = 0; hv < 2; ++hv) {
    u16x8 pk;
#pragma unroll
    for (int k = 0; k < 8; ++k) pk[k] = f2bf(vals[hv * 8 + k]);
    *(u16x8*)((char*)Bbs + ((nB * 128 + (tgB + hv * 8) * 2) ^ ((nB & 7) << 4))) = pk;
  }
  __syncthreads();

  // matmul2: Y = W @ x ; matmul3: G = (fB)^T @ x   (W in Cb, fB^T in Bbs)
  f4v accY[4] = {}, accG[4] = {};
#pragma unroll
  for (int ks = 0; ks < 64; ks += 32) {
    int kb = (ks >> 3) + (lane >> 4);
    int ra = wv * 16 + (lane & 15);
    bfrag afW = *(const bfrag*)((const char*)Cb + ((ra * 128 + kb * 16) ^ ((ra & 7) << 4)));
    bfrag afB = *(const bfrag*)((const char*)Bbs + ((ra * 128 + kb * 16) ^ ((ra & 7) << 4)));
#pragma unroll
    for (int j = 0; j < 4; ++j) {
      int rb = j * 16 + (lane & 15);
      bfrag bg = *(const bfrag*)((const char*)xT + ((rb * 128 + kb * 16) ^ ((rb & 7) << 4)));
      accY[j] = __builtin_amdgcn_mfma_f32_16x16x32_bf16(afW, bg, accY[j], 0, 0, 0);
      accG[j] = __builtin_amdgcn_mfma_f32_16x16x32_bf16(afB, bg, accG[j], 0, 0, 0);
    }
  }
  // fold D*x into Y (reads xT)
  float yout[4][4];
  int trow = wv * 16 + ((lane >> 4) << 2);
#pragma unroll
  for (int j = 0; j < 4; ++j) {
    int p = j * 16 + (lane & 15);
#pragma unroll
    for (int r = 0; r < 4; ++r) {
      int t = trow + r;
      float xval = bf2f(*(const unsigned short*)((const char*)xT + ((p * 128 + t * 2) ^ ((p & 7) << 4))));
      yout[j][r] = accY[j][r] + Dh * xval;
    }
  }
  __syncthreads();  // all LDS reads done

  // stage Y -> Cb space, G -> Bbs space (bf16, row-swizzled [t][p])
#pragma unroll
  for (int j = 0; j < 4; ++j) {
    int p = j * 16 + (lane & 15);
#pragma unroll
    for (int r = 0; r < 4; ++r) {
      int t = trow + r;
      int off = (t * 128 + p * 2) ^ ((t & 7) << 4);
      *(unsigned short*)((char*)Cb + off) = f2bf(yout[j][r]);
      *(unsigned short*)((char*)Bbs + off) = f2bf(accG[j][r]);
    }
  }
  __syncthreads();

  // coalesced global stores
  {
    int r = tid >> 2, colq = (tid & 3) * 16;
    int o0 = (r * 128 + colq * 2) ^ ((r & 7) << 4);
    int o1 = (r * 128 + colq * 2 + 16) ^ ((r & 7) << 4);
    u16x8 yv0 = *(const u16x8*)((const char*)Cb + o0);
    u16x8 yv1 = *(const u16x8*)((const char*)Cb + o1);
    unsigned short* yp = y + ((size_t)(b * Ls + c0 + r)) * DI + h * 64 + colq;
    *(u16x8*)yp = yv0;
    *(u16x8*)(yp + 8) = yv1;
    u16x8 gv0 = *(const u16x8*)((const char*)Bbs + o0);
    u16x8 gv1 = *(const u16x8*)((const char*)Bbs + o1);
    unsigned short* gp = gbuf + ((size_t)blk2 * 64 + r) * 64 + colq;
    *(u16x8*)gp = gv0;
    *(u16x8*)(gp + 8) = gv1;
  }
}

// inter-chunk recurrence, bf16 storage, fp32 accumulator, 2-deep prefetch; grid 256
__global__ __launch_bounds__(256) void k_chain(unsigned short* __restrict__ gbuf,
                                               const float* __restrict__ cumbuf) {
  int blk = blockIdx.x;          // 128 groups x 2 splits
  int grp = blk >> 1, sp = blk & 1;
  size_t base = (size_t)grp * NCH * 4096 + sp * 2048 + (size_t)threadIdx.x * 8;
  const float* cum = cumbuf + (size_t)grp * NCH * 64 + 63;
  float hv[8] = {};
  u16x8 g0 = *(const u16x8*)(gbuf + base);
  u16x8 g1 = *(const u16x8*)(gbuf + base + 4096);
  float P0 = cum[0], P1 = cum[64];
  for (int c = 0; c < NCH; ++c) {
    u16x8 g2 = {};
    float P2 = 0.f;
    if (c + 2 < NCH) {
      g2 = *(const u16x8*)(gbuf + base + (size_t)(c + 2) * 4096);
      P2 = cum[(size_t)(c + 2) * 64];
    }
    u16x8 o;
#pragma unroll
    for (int k = 0; k < 8; ++k) o[k] = f2bf(hv[k]);
    *(u16x8*)(gbuf + base + (size_t)c * 4096) = o;
#pragma unroll
    for (int k = 0; k < 8; ++k) hv[k] = fmaf(P0, hv[k], bf2f(g0[k]));
    g0 = g1; g1 = g2; P0 = P1; P1 = P2;
  }
}

// correction: Y[t][p] += exp(L[t]) * sum_n C[t][n] * hin[n][p]; grid 2048
__global__ __launch_bounds__(256) void k_corr(const unsigned short* __restrict__ bcbuf,
    const unsigned short* __restrict__ gbuf, const float* __restrict__ cumbuf,
    unsigned short* __restrict__ yF, unsigned short* __restrict__ yR) {
  int blk2 = blockIdx.x;
  int c = blk2 & 15;
  if (c == 0) return;
  __shared__ unsigned short Ct[4096], HT[4096];
  __shared__ float cdl[64];
  int dir = blk2 >> 10;
  int bh = (blk2 & 1023) >> 4, h = bh & 15, b = bh >> 4;
  int tid = threadIdx.x, wv = tid >> 6, lane = tid & 63;
  int c0 = c * CH;
  unsigned short* y = dir ? yR : yF;
  {
    int r = tid >> 2;
    int colq = (tid & 3) * 16;
    const unsigned short* bc = bcbuf + ((size_t)(dir * TOK + b * Ls + c0 + r)) * 128 + 64 + colq;
    u16x8 v0 = *(const u16x8*)bc;
    u16x8 v1 = *(const u16x8*)(bc + 8);
    *(u16x8*)((char*)Ct + ((r * 128 + colq * 2) ^ ((r & 7) << 4))) = v0;
    *(u16x8*)((char*)Ct + ((r * 128 + colq * 2 + 16) ^ ((r & 7) << 4))) = v1;
  }
  {
    int n = tid >> 2, p0 = (tid & 3) * 16;
    const unsigned short* hr = gbuf + (size_t)blk2 * 4096 + (size_t)n * 64 + p0;
    u16x8 v0 = *(const u16x8*)hr;
    u16x8 v1 = *(const u16x8*)(hr + 8);
#pragma unroll
    for (int k = 0; k < 8; ++k) {
      int p = p0 + k;
      *(unsigned short*)((char*)HT + ((p * 128 + n * 2) ^ ((p & 7) << 4))) = v0[k];
      int p2 = p0 + 8 + k;
      *(unsigned short*)((char*)HT + ((p2 * 128 + n * 2) ^ ((p2 & 7) << 4))) = v1[k];
    }
  }
  if (tid < 64) cdl[tid] = cumbuf[(size_t)blk2 * 64 + tid];
  __syncthreads();

  f4v acc[4] = {};
#pragma unroll
  for (int ks = 0; ks < 64; ks += 32) {
    int kb = (ks >> 3) + (lane >> 4);
    int ra = wv * 16 + (lane & 15);
    bfrag af = *(const bfrag*)((const char*)Ct + ((ra * 128 + kb * 16) ^ ((ra & 7) << 4)));
#pragma unroll
    for (int j = 0; j < 4; ++j) {
      int rb = j * 16 + (lane & 15);
      bfrag bg = *(const bfrag*)((const char*)HT + ((rb * 128 + kb * 16) ^ ((rb & 7) << 4)));
      acc[j] = __builtin_amdgcn_mfma_f32_16x16x32_bf16(af, bg, acc[j], 0, 0, 0);
    }
  }
  __syncthreads();  // done reading Ct/HT

  // stage cdl-scaled correction into Ct space (bf16, row-swizzled [t][p])
  int trow = wv * 16 + ((lane >> 4) << 2);
#pragma unroll
  for (int j = 0; j < 4; ++j) {
    int p = j * 16 + (lane & 15);
#pragma unroll
    for (int r = 0; r < 4; ++r) {
      int t = trow + r;
      *(unsigned short*)((char*)Ct + ((t * 128 + p * 2) ^ ((t & 7) << 4))) = f2bf(cdl[t] * acc[j][r]);
    }
  }
  __syncthreads();

  // coalesced RMW
  {
    int r = tid >> 2, colq = (tid & 3) * 16;
    u16x8 c0v = *(const u16x8*)((const char*)Ct + ((r * 128 + colq * 2) ^ ((r & 7) << 4)));
    u16x8 c1v = *(const u16x8*)((const char*)Ct + ((r * 128 + colq * 2 + 16) ^ ((r & 7) << 4)));
    unsigned short* yp = y + ((size_t)(b * Ls + c0 + r)) * DI + h * 64 + colq;
    u16x8 y0 = *(const u16x8*)yp;
    u16x8 y1 = *(const u16x8*)(yp + 8);
#pragma unroll
    for (int k = 0; k < 8; ++k) {
      y0[k] = f2bf(bf2f(y0[k]) + bf2f(c0v[k]));
      y1[k] = f2bf(bf2f(y1[k]) + bf2f(c1v[k]));
    }
    *(u16x8*)yp = y0;
    *(u16x8*)(yp + 8) = y1;
  }
}
// ================================================================

// ---- both-direction gated RMSNorm: ybf[w] = 0.5*(gate_f(w) + gate_r(flip(w))) ----
__global__ __launch_bounds__(256) void k_gab(const unsigned short* __restrict__ yF,
    const unsigned short* __restrict__ yR, const unsigned short* __restrict__ zxb,
    const float* __restrict__ nwF, const float* __restrict__ nwR,
    const int* __restrict__ len, unsigned short* __restrict__ ybf) {
  int w = (blockIdx.x * 256 + threadIdx.x) >> 6;
  int lane = threadIdx.x & 63;
  if (w >= TOK) return;
  int t = w & (Ls - 1), b = w >> 10;
  int ln = len[b];
  int r = b * Ls + ((t < ln) ? (ln - 1 - t) : t);
  const unsigned short* yf = yF + (size_t)w * DI;
  const unsigned short* yr = yR + (size_t)r * DI;
  const unsigned short* zr = zxb + (size_t)w * NPJ;
  float gf[16], gr[16];
  float ssf = 0.f, ssr = 0.f;
#pragma unroll
  for (int q = 0; q < 4; ++q) {
    ushort4 yv = *(const ushort4*)(yf + lane * 4 + q * 256);
    ushort4 rv = *(const ushort4*)(yr + lane * 4 + q * 256);
    ushort4 zu = *(const ushort4*)(zr + lane * 4 + q * 256);
    float z0 = bf2f(zu.x), z1 = bf2f(zu.y), z2 = bf2f(zu.z), z3 = bf2f(zu.w);
    float s0 = z0 * sigmoidf_(z0), s1 = z1 * sigmoidf_(z1), s2 = z2 * sigmoidf_(z2), s3 = z3 * sigmoidf_(z3);
    gf[4 * q + 0] = bf2f(yv.x) * s0; gf[4 * q + 1] = bf2f(yv.y) * s1;
    gf[4 * q + 2] = bf2f(yv.z) * s2; gf[4 * q + 3] = bf2f(yv.w) * s3;
    gr[4 * q + 0] = bf2f(rv.x) * s0; gr[4 * q + 1] = bf2f(rv.y) * s1;
    gr[4 * q + 2] = bf2f(rv.z) * s2; gr[4 * q + 3] = bf2f(rv.w) * s3;
#pragma unroll
    for (int j = 0; j < 4; ++j) {
      ssf += gf[4 * q + j] * gf[4 * q + j];
      ssr += gr[4 * q + j] * gr[4 * q + j];
    }
  }
  ssf = wsum(ssf);
  ssr = wsum(ssr);
  float scf = 0.5f * rsqrtf(ssf * (1.f / (float)DI) + EPSf);
  float scr = 0.5f * rsqrtf(ssr * (1.f / (float)DI) + EPSf);
#pragma unroll
  for (int q = 0; q < 4; ++q) {
    float4 nf = *(const float4*)(nwF + lane * 4 + q * 256);
    float4 nr = *(const float4*)(nwR + lane * 4 + q * 256);
    float o0 = gf[4 * q + 0] * scf * nf.x + gr[4 * q + 0] * scr * nr.x;
    float o1 = gf[4 * q + 1] * scf * nf.y + gr[4 * q + 1] * scr * nr.y;
    float o2 = gf[4 * q + 2] * scf * nf.z + gr[4 * q + 2] * scr * nr.z;
    float o3 = gf[4 * q + 3] * scf * nf.w + gr[4 * q + 3] * scr * nr.w;
    *(ushort4*)(ybf + (size_t)w * DI + lane * 4 + q * 256) =
        make_ushort4(f2bf(o0), f2bf(o1), f2bf(o2), f2bf(o3));
  }
}

// ---- hnbf = LN(src) bf16 (heads input); rows t==0 also -> cell out (fp32) + cc0 ----
__global__ __launch_bounds__(256) void k_hl2(const float* __restrict__ src,
    unsigned short* __restrict__ dstbf, float* __restrict__ cellout, float* __restrict__ cc0) {
  int gw = (blockIdx.x * 256 + threadIdx.x) >> 6;
  int lane = threadIdx.x & 63;
  if (gw >= TOK) return;
  float x[8];
  ld8(src + (size_t)gw * DM, lane, x);
  norm8(x);
  st8bf(dstbf + (size_t)gw * DM, lane, x);
  if ((gw & (Ls - 1)) == 0) {
    int b = gw >> 10;
    st8(cellout + (size_t)b * DM, lane, x);
    st8(cc0 + (size_t)b * DM, lane, x);
  }
}

// ---- lengths ----
__global__ __launch_bounds__(256) void k_lengths(const unsigned char* __restrict__ mask, int* __restrict__ len) {
  int b = blockIdx.x;
  int tid = threadIdx.x;
  int cnt = 0;
  for (int t = tid; t < Ls; t += 256) cnt += mask[b * Ls + t] ? 0 : 1;
#pragma unroll
  for (int o = 32; o > 0; o >>= 1) cnt += __shfl_xor(cnt, o);
  __shared__ int red[4];
  if ((tid & 63) == 0) red[tid >> 6] = cnt;
  __syncthreads();
  if (tid == 0) len[b] = red[0] + red[1] + red[2] + red[3];
}

// ---- mlm head (bf16 input) ----
__global__ __launch_bounds__(256) void k_mlm(const unsigned short* __restrict__ e2,
                                             const float* __restrict__ w3,
                                             const float* __restrict__ b3, float* __restrict__ out) {
  int gw = (blockIdx.x * 256 + threadIdx.x) >> 6;
  int lane = threadIdx.x & 63;
  if (gw >= TOK) return;
  float x[8], w[8];
  ld8bf(e2 + (size_t)gw * DM, lane, x);
  ld8(w3, lane, w);
  float s = 0;
#pragma unroll
  for (int j = 0; j < 8; ++j) s += x[j] * w[j];
  s = wsum(s);
  if (lane == 0) out[gw] = s + b3[0];
}

// ---- classifier matvec (wave-per-output; optional LN+affine on input) ----
__global__ __launch_bounds__(256) void k_clsmv(const float* __restrict__ xin, size_t xstride,
    const float* __restrict__ g, const float* __restrict__ bb, int doLN,
    const float* __restrict__ W, const float* __restrict__ bias, int doRelu,
    float* __restrict__ out, int nout) {
  int b = blockIdx.y;
  int j = blockIdx.x * 4 + (threadIdx.x >> 6);
  int lane = threadIdx.x & 63;
  if (j >= nout) return;
  float x[8];
  ld8(xin + (size_t)b * xstride, lane, x);
  if (doLN) {
    norm8(x);
    float gv[8], bv[8];
    ld8(g, lane, gv); ld8(bb, lane, bv);
#pragma unroll
    for (int k = 0; k < 8; ++k) x[k] = x[k] * gv[k] + bv[k];
  }
  float w[8];
  ld8(W + (size_t)j * DM, lane, w);
  float s = 0;
#pragma unroll
  for (int k = 0; k < 8; ++k) s += x[k] * w[k];
  s = wsum(s);
  if (lane == 0) {
    float v = s + bias[j];
    if (doRelu) v = fmaxf(v, 0.f);
    out[(size_t)b * nout + j] = v;
  }
}

// ---- workspace layout (floats) ----
constexpr size_t F_H   = 0;
constexpr size_t F_DTF = F_H + (size_t)TOK * DM;
constexpr size_t F_LAF = F_DTF + (size_t)TOK * NH;
constexpr size_t F_DTR = F_LAF + (size_t)TOK * NH;
constexpr size_t F_LAR = F_DTR + (size_t)TOK * NH;
constexpr size_t F_ON  = F_LAR + (size_t)TOK * NH;
constexpr size_t F_CUM = F_ON + (size_t)TOK * DM;
constexpr size_t F_CC0 = F_CUM + (size_t)2 * Bb * NH * NCH * 64;
constexpr size_t F_CC1 = F_CC0 + Bb * DM;
constexpr size_t F_CC2 = F_CC1 + Bb * DM;
constexpr size_t F_LEN = F_CC2 + Bb * DM;
constexpr size_t F_END = F_LEN + 16;
// bf16 regions (ushort offsets)
constexpr size_t U0     = F_END * 2;
constexpr size_t UW_IN  = U0;
constexpr size_t UW_OUT = UW_IN + (size_t)2 * DIP * DM;
constexpr size_t UW_VE  = UW_OUT + (size_t)2 * DM * DI;
constexpr size_t UW_E1  = UW_VE + (size_t)DM * DM;
constexpr size_t UW_E2  = UW_E1 + (size_t)DM * DM;
constexpr size_t U_BFA  = UW_E2 + (size_t)DM * DM;   // v1 / e1-bf16
constexpr size_t U_HNBF = U_BFA + (size_t)TOK * DM;
constexpr size_t U_YBF  = U_HNBF + (size_t)TOK * DM;
constexpr size_t U_ZX   = U_YBF + (size_t)TOK * DI;   // bf16 zx (TOK*NPJ)
constexpr size_t U_YF   = U_ZX + (size_t)TOK * NPJ;   // bf16 y fwd
constexpr size_t U_YR   = U_YF + (size_t)TOK * DI;    // bf16 y rev
constexpr size_t U_G    = U_YR + (size_t)TOK * DI;    // bf16 G/hin (2*1024*4096)

extern "C" void kernel_launch(void* const* d_in, const int* in_sizes, int n_in,
                              void* d_out, int out_size, void* d_ws, size_t ws_size,
                              hipStream_t stream) {
  const int* src = (const int*)d_in[0];
  const float* values = (const float*)d_in[1];
  const unsigned char* mask = (const unsigned char*)d_in[2];
  const float* embed = (const float*)d_in[3];
  const float* ge_g = (const float*)d_in[4];
  const float* ge_b = (const float*)d_in[5];
  const float* ve_w1 = (const float*)d_in[6];
  const float* ve_b1 = (const float*)d_in[7];
  const float* ve_w2 = (const float*)d_in[8];
  const float* ve_b2 = (const float*)d_in[9];
  const float* ve_g = (const float*)d_in[10];
  const float* ve_bb = (const float*)d_in[11];
  const float* in_w = (const float*)d_in[12];
  const float* conv_w_f = (const float*)d_in[13];
  const float* conv_b_f = (const float*)d_in[14];
  const float* A_f = (const float*)d_in[15];
  const float* dtb_f = (const float*)d_in[16];
  const float* D_f = (const float*)d_in[17];
  const float* nw_f = (const float*)d_in[18];
  const float* conv_w_r = (const float*)d_in[19];
  const float* conv_b_r = (const float*)d_in[20];
  const float* A_r = (const float*)d_in[21];
  const float* dtb_r = (const float*)d_in[22];
  const float* D_r = (const float*)d_in[23];
  const float* nw_r = (const float*)d_in[24];
  const float* out_w = (const float*)d_in[25];
  const float* expr_w1 = (const float*)d_in[26];
  const float* expr_b1 = (const float*)d_in[27];
  const float* expr_w2 = (const float*)d_in[28];
  const float* expr_b2 = (const float*)d_in[29];
  const float* expr_w3 = (const float*)d_in[30];
  const float* expr_b3 = (const float*)d_in[31];
  const float* cls_w1 = (const float*)d_in[32];
  const float* cls_b1 = (const float*)d_in[33];
  const float* cls_g1 = (const float*)d_in[34];
  const float* cls_bb1 = (const float*)d_in[35];
  const float* cls_w2 = (const float*)d_in[36];
  const float* cls_b2 = (const float*)d_in[37];
  const float* cls_g2 = (const float*)d_in[38];
  const float* cls_bb2 = (const float*)d_in[39];
  const float* cls_wo = (const float*)d_in[40];
  const float* cls_bo = (const float*)d_in[41];

  float* ws = (float*)d_ws;
  unsigned short* wsu = (unsigned short*)d_ws;
  float* h = ws + F_H;
  float* dtf = ws + F_DTF;
  float* laf = ws + F_LAF;
  float* dtr = ws + F_DTR;
  float* lar = ws + F_LAR;
  float* onew = ws + F_ON;
  float* cumb = ws + F_CUM;
  float* cc0 = ws + F_CC0;
  float* cc1 = ws + F_CC1;
  float* cc2 = ws + F_CC2;
  int* len = (int*)(ws + F_LEN);
  unsigned short* w_in = wsu + UW_IN;
  unsigned short* w_out = wsu + UW_OUT;
  unsigned short* w_ve = wsu + UW_VE;
  unsigned short* w_e1 = wsu + UW_E1;
  unsigned short* w_e2 = wsu + UW_E2;
  unsigned short* bfa = wsu + U_BFA;
  unsigned short* hnbf = wsu + U_HNBF;
  unsigned short* ybf = wsu + U_YBF;
  unsigned short* zxb = wsu + U_ZX;
  unsigned short* yFb = wsu + U_YF;
  unsigned short* yRb = wsu + U_YR;
  unsigned short* gbuf = wsu + U_G;
  unsigned short* bcbuf = ybf;      // reuse: bcbuf (2*TOK*128) lives in ybf until gab writes it
  float* t2 = onew;                 // reuse before layers
  unsigned short* e2b = zxb;        // reuse after layers
  float* out = (float*)d_out;

  // ---- weight conversions (single launch) ----
  {
    int n0 = 2 * DIP * DM / 8, n1 = 2 * DM * DI / 8, n2 = DM * DM / 8, n3 = n2, n4 = n2;
    int tot = n0 + n1 + n2 + n3 + n4;
    k_w2bf5<<<(tot + 255) / 256, 256, 0, stream>>>(in_w, w_in, n0, out_w, w_out, n1,
                                                   ve_w2, w_ve, n2, expr_w1, w_e1, n3,
                                                   expr_w2, w_e2, n4);
  }

  // ---- embedding + value encoder ----
  k_embed<<<TOK / 4, 256, 0, stream>>>(src, values, embed, ge_g, ge_b, ve_w1, ve_b1, h, bfa);
  gemm_bf<0, 0><<<dim3(DM / 128, TOK / 128), 256, 0, stream>>>(bfa, w_ve, ve_b2, t2, TOK, DM, DM);
  k_haddv<<<TOK / 4, 256, 0, stream>>>(t2, ve_g, ve_bb, mask, h);
  k_lengths<<<Bb, 256, 0, stream>>>(mask, len);

  // ---- layers ----
  for (int i = 0; i < 2; ++i) {
    const float* inw = in_w + (size_t)i * DIP * DM;
    unsigned short* inwb = w_in + (size_t)i * DIP * DM;
    unsigned short* outwb = w_out + (size_t)i * DM * DI;
    const float* cwF = conv_w_f + (size_t)i * CDIM * 4;
    const float* cbF = conv_b_f + (size_t)i * CDIM;
    const float* cwR = conv_w_r + (size_t)i * CDIM * 4;
    const float* cbR = conv_b_r + (size_t)i * CDIM;
    const float* pre = (i == 0) ? h : onew;
    k_lndt<<<TOK / 4, 256, 0, stream>>>(pre, inw, dtb_f + i * NH, A_f + i * NH,
                                        dtb_r + i * NH, A_r + i * NH, len, hnbf,
                                        dtf, laf, dtr, lar);
    gemm_bf<0, 1><<<dim3(NPJ / 128, TOK / 128), 256, 0, stream>>>(hnbf, inwb, nullptr, zxb, TOK, NPJ, DM);
    k_convbc<<<(2 * TOK * 128) / 256, 256, 0, stream>>>(zxb, cwF, cbF, cwR, cbR, len, bcbuf);
    k_chunk<<<2 * Bb * NH * NCH, 256, 0, stream>>>(zxb, bcbuf, cwF, cbF, cwR, cbR,
        dtf, laf, dtr, lar, D_f + i * NH, D_r + i * NH, len, yFb, yRb, gbuf, cumb);
    k_chain<<<2 * 2 * Bb * NH, 256, 0, stream>>>(gbuf, cumb);
    k_corr<<<2 * Bb * NH * NCH, 256, 0, stream>>>(bcbuf, gbuf, cumb, yFb, yRb);
    k_gab<<<TOK / 4, 256, 0, stream>>>(yFb, yRb, zxb, nw_f + (size_t)i * DI, nw_r + (size_t)i * DI,
                                       len, ybf);
    gemm_bf<0, 0><<<dim3(DM / 128, TOK / 128), 256, 0, stream>>>(ybf, outwb, nullptr, onew, TOK, DM, DI);
  }

  // ---- heads ----
  k_hl2<<<TOK / 4, 256, 0, stream>>>(onew, hnbf, out + TOK, cc0);
  gemm_bf<2, 1><<<dim3(DM / 128, TOK / 128), 256, 0, stream>>>(hnbf, w_e1, expr_b1, bfa, TOK, DM, DM);
  gemm_bf<2, 1><<<dim3(DM / 128, TOK / 128), 256, 0, stream>>>(bfa, w_e2, expr_b2, e2b, TOK, DM, DM);
  k_mlm<<<TOK / 4, 256, 0, stream>>>(e2b, expr_w3, expr_b3, out);
  k_clsmv<<<dim3(128, Bb), 256, 0, stream>>>(cc0, DM, nullptr, nullptr, 0,
                                             cls_w1, cls_b1, 1, cc1, DM);
  k_clsmv<<<dim3(128, Bb), 256, 0, stream>>>(cc1, DM, cls_g1, cls_bb1, 1,
                                             cls_w2, cls_b2, 1, cc2, DM);
  k_clsmv<<<dim3(41, Bb), 256, 0, stream>>>(cc2, DM, cls_g2, cls_bb2, 1,
                                            cls_wo, cls_bo, 0, out + TOK + Bb * DM, 164);
}